// Round 6
// baseline (292.293 us; speedup 1.0000x reference)
//
#include <hip/hip_runtime.h>
#include <math.h>

#define Bn 8
#define Nn 2048
#define FIn 256
#define FOn 128

typedef __attribute__((ext_vector_type(8))) short short8;
typedef __attribute__((ext_vector_type(4))) float f32x4;
typedef __attribute__((ext_vector_type(4))) unsigned short ushort4v;

__device__ __forceinline__ unsigned short f2bf(float x){
    union { float f; unsigned u; } v; v.f = x;
    unsigned r = v.u + 0x7fffu + ((v.u >> 16) & 1u);
    return (unsigned short)(r >> 16);
}

// K0: WT[o][k] = bf16(W[k][o])   (128 x 256)
__global__ void k0_wt(const float* __restrict__ W, unsigned short* __restrict__ WT){
    int o = blockIdx.x, k = threadIdx.x;
    WT[o*FIn + k] = f2bf(W[k*FOn + o]);
}

// K1: Wh = h @ W via bf16 MFMA; emits WhT (bf16, transposed) + s1/s2.
// 32 rows/block, grid 512 (2 blocks/CU). 4 waves = 2 row-groups x 2 col-halves.
__global__ __launch_bounds__(256) void k1_gemm(const float* __restrict__ h,
        const unsigned short* __restrict__ WT, const float* __restrict__ a,
        unsigned short* __restrict__ WhT, float* __restrict__ s1, float* __restrict__ s2){
    __shared__ __align__(16) unsigned short tr[128][48];
    __shared__ float ps1[2][32], ps2[2][32];
    int t = threadIdx.x, lane = t & 63, w = t >> 6;
    int rg = w >> 1, ch = w & 1;
    int l16 = lane & 15, khalf = (lane >> 4) * 8;
    long g0 = (long)blockIdx.x * 32;
    int b = (int)(g0 >> 11);
    int i0 = (int)(g0 & 2047);
    long row = g0 + rg*16 + l16;
    f32x4 acc[4];
    #pragma unroll
    for (int nf=0;nf<4;nf++) acc[nf] = (f32x4){0.f,0.f,0.f,0.f};
    #pragma unroll
    for (int ks=0; ks<8; ks++){
        int kb = ks*32 + khalf;
        const float4* hp = (const float4*)(h + row*FIn + kb);
        float4 h0 = hp[0], h1 = hp[1];
        short8 af;
        af[0]=(short)f2bf(h0.x); af[1]=(short)f2bf(h0.y); af[2]=(short)f2bf(h0.z); af[3]=(short)f2bf(h0.w);
        af[4]=(short)f2bf(h1.x); af[5]=(short)f2bf(h1.y); af[6]=(short)f2bf(h1.z); af[7]=(short)f2bf(h1.w);
        #pragma unroll
        for (int nf=0;nf<4;nf++){
            short8 bfv = *(const short8*)(WT + (ch*64 + nf*16 + l16)*FIn + kb);
            acc[nf] = __builtin_amdgcn_mfma_f32_16x16x32_bf16(af, bfv, acc[nf], 0, 0, 0);
        }
    }
    {
        float a1v[4], a2v[4];
        #pragma unroll
        for (int nf=0;nf<4;nf++){
            a1v[nf] = a[ch*64 + nf*16 + l16];
            a2v[nf] = a[FOn + ch*64 + nf*16 + l16];
        }
        #pragma unroll
        for (int r=0;r<4;r++){
            float u1 = 0.f, u2 = 0.f;
            #pragma unroll
            for (int nf=0;nf<4;nf++){ u1 = fmaf(acc[nf][r], a1v[nf], u1); u2 = fmaf(acc[nf][r], a2v[nf], u2); }
            u1 += __shfl_xor(u1, 1); u1 += __shfl_xor(u1, 2); u1 += __shfl_xor(u1, 4); u1 += __shfl_xor(u1, 8);
            u2 += __shfl_xor(u2, 1); u2 += __shfl_xor(u2, 2); u2 += __shfl_xor(u2, 4); u2 += __shfl_xor(u2, 8);
            if (l16 == 0){
                int rloc = rg*16 + ((lane>>4)<<2) + r;
                ps1[ch][rloc] = u1; ps2[ch][rloc] = u2;
            }
        }
    }
    int rbase = rg*16 + ((lane>>4)<<2);
    #pragma unroll
    for (int nf=0;nf<4;nf++)
        #pragma unroll
        for (int r=0;r<4;r++)
            tr[ch*64 + nf*16 + l16][rbase + r] = f2bf(acc[nf][r]);
    __syncthreads();
    if (t < 32){
        s1[g0 + t] = ps1[0][t] + ps1[1][t];
        s2[g0 + t] = ps2[0][t] + ps2[1][t];
    }
    int o = t >> 1, seg = t & 1;
    short8 v0 = *(const short8*)&tr[o][seg*16];
    short8 v1 = *(const short8*)&tr[o][seg*16 + 8];
    unsigned short* dst = WhT + ((long)(b*FOn + o))*Nn + i0 + seg*16;
    *(short8*)(dst)     = v0;
    *(short8*)(dst + 8) = v1;
}

// K2: s2max[b] = max_j s2[b][j]  (8 blocks x 256 threads)
__global__ __launch_bounds__(256) void k2_s2max(const float* __restrict__ s2, float* __restrict__ s2m){
    __shared__ float red[4];
    int b = blockIdx.x, t = threadIdx.x;
    float m = -1e30f;
    #pragma unroll
    for (int k=0;k<8;k++) m = fmaxf(m, s2[b*Nn + t + k*256]);
    m = fmaxf(m, __shfl_xor(m, 1));
    m = fmaxf(m, __shfl_xor(m, 2));
    m = fmaxf(m, __shfl_xor(m, 4));
    m = fmaxf(m, __shfl_xor(m, 8));
    m = fmaxf(m, __shfl_xor(m, 16));
    m = fmaxf(m, __shfl_xor(m, 32));
    if ((t & 63) == 0) red[t >> 6] = m;
    __syncthreads();
    if (t == 0) s2m[b] = fmaxf(fmaxf(red[0], red[1]), fmaxf(red[2], red[3]));
}

// K3 v6: round-4 skeleton + global-shift softmax + ballot-packed adj in LDS.
// Block = (b, 32-row i-tile), 512 threads = 8 waves, grid 512 (2 blocks/CU).
// Prologue: burst-read this block's 32 adj rows (256KB, coalesced, 128 independent
// wave-iters) -> __ballot -> 8KB LDS bitmask. Loop has ZERO global loads for adj.
// Scores: p = bit ? exp(leaky(s1+s2) - Mx) : 0, Mx = leaky(s1 + s2max[b]) (exact
// row upper bound, softmax shift-invariant). No online state, no shfl in loop,
// no rescale. V: reg-prefetch -> LDS parity dbuf. 1 barrier/tile.
__global__ __launch_bounds__(512) void k3_flash(const int* __restrict__ adj,
        const unsigned short* __restrict__ WhT, const float* __restrict__ s1g,
        const float* __restrict__ s2g, const float* __restrict__ s2m,
        float* __restrict__ out){
    __shared__ __align__(16) unsigned short vt[2][128][72];
    __shared__ __align__(16) unsigned short pt[2][32][72];
    __shared__ unsigned long long ajw64[1024];    // 32 rows x 2048 bits = 8KB
    __shared__ float s2t[Nn];
    __shared__ float l_s[32];
    int t = threadIdx.x, lane = t & 63, w = t >> 6;
    int bid = blockIdx.x;
    int b = bid & 7;                 // XCD pin: per-b WhT slice resident in one L2
    int i0 = (bid >> 3) * 32;
    int q = t >> 4, c = t & 15;      // score row / col-group
    int rg = w >> 2, cq = w & 3;     // MFMA wave tile: rows rg*16.., cols cq*32..
    int l16 = lane & 15, khalf = (lane >> 4) * 8;
    *(float4*)&s2t[t*4] = *(const float4*)(s2g + b*Nn + t*4);
    float s1r = s1g[b*Nn + i0 + q];
    float Mx = s1r + s2m[b];
    Mx = fmaxf(Mx, 0.2f*Mx);         // leaky(s1r + s2max) >= every score in row
    // V depth-1 prefetch (rows vrow, vrow+64 at j-seg vj)
    int vrow = t >> 3, vj = (t & 7) * 8;
    const unsigned short* vp0 = WhT + ((long)(b*FOn + vrow))*Nn + vj;
    const unsigned short* vp1 = vp0 + 64*Nn;
    short8 vA0 = *(const short8*)(vp0);
    short8 vA1 = *(const short8*)(vp1);
    // ---- adj burst-pack: wave w covers word-pairs p = w*128 .. w*128+127 ----
    const int* ajrow = adj + ((long)(b*Nn + i0))*Nn;
    #pragma unroll 8
    for (int i = 0; i < 128; i++){
        int p = w*128 + i;                       // p>>5 = row, p&31 = 64-col chunk
        int av = ajrow[(long)(p >> 5)*Nn + (p & 31)*64 + lane];
        unsigned long long mask = __ballot(av > 0);
        if (lane == 0) ajw64[p] = mask;
    }
    float lsum = 0.f;
    f32x4 acc0 = (f32x4){0.f,0.f,0.f,0.f};
    f32x4 acc1 = (f32x4){0.f,0.f,0.f,0.f};
    const unsigned* ajw32 = (const unsigned*)ajw64;
    __syncthreads();

    #pragma unroll 1
    for (int jt = 0; jt < 32; jt++){
        int j0 = jt*64;
        int par = jt & 1;
        // V regs -> LDS, re-issue next tile
        *(short8*)&vt[par][vrow][vj]      = vA0;
        *(short8*)&vt[par][vrow + 64][vj] = vA1;
        int jn = (jt < 31) ? j0 + 64 : j0;
        vA0 = *(const short8*)(vp0 + jn);
        vA1 = *(const short8*)(vp1 + jn);
        // scores from LDS bitmask (broadcast read) + s2t
        unsigned word = ajw32[q*64 + jt*2 + (c >> 3)];
        unsigned nib = (word >> ((c & 7)*4)) & 15u;
        float4 s2c = *(const float4*)&s2t[j0 + c*4];
        float x0 = s1r + s2c.x; x0 = fmaxf(x0, 0.2f*x0);
        float x1 = s1r + s2c.y; x1 = fmaxf(x1, 0.2f*x1);
        float x2 = s1r + s2c.z; x2 = fmaxf(x2, 0.2f*x2);
        float x3 = s1r + s2c.w; x3 = fmaxf(x3, 0.2f*x3);
        float p0 = (nib & 1u) ? __expf(x0 - Mx) : 0.f;
        float p1 = (nib & 2u) ? __expf(x1 - Mx) : 0.f;
        float p2 = (nib & 4u) ? __expf(x2 - Mx) : 0.f;
        float p3 = (nib & 8u) ? __expf(x3 - Mx) : 0.f;
        lsum += (p0 + p1) + (p2 + p3);
        ushort4v pv;
        pv[0] = f2bf(p0); pv[1] = f2bf(p1); pv[2] = f2bf(p2); pv[3] = f2bf(p3);
        *(ushort4v*)&pt[par][q][c*4] = pv;
        __syncthreads();
        // MFMA (wave: rows rg*16..+15, cols cq*32..+31), no rescale
        #pragma unroll
        for (int kk=0;kk<2;kk++){
            short8 af = *(const short8*)&pt[par][rg*16 + l16][kk*32 + khalf];
            short8 b0 = *(const short8*)&vt[par][cq*32 + l16][kk*32 + khalf];
            short8 b1 = *(const short8*)&vt[par][cq*32 + 16 + l16][kk*32 + khalf];
            acc0 = __builtin_amdgcn_mfma_f32_16x16x32_bf16(af, b0, acc0, 0, 0, 0);
            acc1 = __builtin_amdgcn_mfma_f32_16x16x32_bf16(af, b1, acc1, 0, 0, 0);
        }
    }
    // single row-sum reduction for the whole kernel
    lsum += __shfl_xor(lsum, 1);
    lsum += __shfl_xor(lsum, 2);
    lsum += __shfl_xor(lsum, 4);
    lsum += __shfl_xor(lsum, 8);
    if (c == 0) l_s[q] = lsum;
    __syncthreads();
    // epilogue: /l, elu, store fp32
    int rb = rg*16 + ((lane>>4)<<2);
    #pragma unroll
    for (int reg=0;reg<4;reg++){
        int r = rb + reg;
        float inv = 1.f / l_s[r];
        float v0 = acc0[reg] * inv;
        float v1 = acc1[reg] * inv;
        v0 = v0 > 0.f ? v0 : (__expf(v0) - 1.f);
        v1 = v1 > 0.f ? v1 : (__expf(v1) - 1.f);
        out[((long)(b*Nn + i0 + r))*FOn + cq*32 + l16]      = v0;
        out[((long)(b*Nn + i0 + r))*FOn + cq*32 + 16 + l16] = v1;
    }
}

extern "C" void kernel_launch(void* const* d_in, const int* in_sizes, int n_in,
                              void* d_out, int out_size, void* d_ws, size_t ws_size,
                              hipStream_t stream){
    const float* h  = (const float*)d_in[0];
    const int* adj  = (const int*)d_in[1];
    const float* W  = (const float*)d_in[2];
    const float* a  = (const float*)d_in[3];
    float* out = (float*)d_out;
    char* ws = (char*)d_ws;
    unsigned short* WT  = (unsigned short*)(ws);                   //    65,536 B
    unsigned short* WhT = (unsigned short*)(ws + 65536);           // 4,194,304 B
    float* s1           = (float*)(ws + 65536 + 4194304);          //    65,536 B
    float* s2           = (float*)(ws + 65536 + 4194304 + 65536);  //    65,536 B
    float* s2m          = (float*)(ws + 65536 + 4194304 + 131072); //        32 B

    k0_wt    <<<128, 256, 0, stream>>>(W, WT);
    k1_gemm  <<<512, 256, 0, stream>>>(h, WT, a, WhT, s1, s2);
    k2_s2max <<<Bn,  256, 0, stream>>>(s2, s2m);
    k3_flash <<<512, 512, 0, stream>>>(adj, WhT, s1, s2, s2m, out);
}

// Round 8
// 229.660 us; speedup vs baseline: 1.2727x; 1.2727x over previous
//
#include <hip/hip_runtime.h>
#include <math.h>

#define Bn 8
#define Nn 2048
#define FIn 256
#define FOn 128

typedef __attribute__((ext_vector_type(8))) short short8;
typedef __attribute__((ext_vector_type(4))) float f32x4;
typedef __attribute__((ext_vector_type(4))) unsigned short ushort4v;

__device__ __forceinline__ unsigned short f2bf(float x){
    union { float f; unsigned u; } v; v.f = x;
    unsigned r = v.u + 0x7fffu + ((v.u >> 16) & 1u);
    return (unsigned short)(r >> 16);
}

// K0: WT[o][k] = bf16(W[k][o])   (128 x 256)
__global__ void k0_wt(const float* __restrict__ W, unsigned short* __restrict__ WT){
    int o = blockIdx.x, k = threadIdx.x;
    WT[o*FIn + k] = f2bf(W[k*FOn + o]);
}

// K1: Wh = h @ W via bf16 MFMA; emits WhT (bf16, transposed) + s1/s2.
// 32 rows/block, grid 512 (2 blocks/CU). 4 waves = 2 row-groups x 2 col-halves.
__global__ __launch_bounds__(256) void k1_gemm(const float* __restrict__ h,
        const unsigned short* __restrict__ WT, const float* __restrict__ a,
        unsigned short* __restrict__ WhT, float* __restrict__ s1, float* __restrict__ s2){
    __shared__ __align__(16) unsigned short tr[128][48];
    __shared__ float ps1[2][32], ps2[2][32];
    int t = threadIdx.x, lane = t & 63, w = t >> 6;
    int rg = w >> 1, ch = w & 1;
    int l16 = lane & 15, khalf = (lane >> 4) * 8;
    long g0 = (long)blockIdx.x * 32;
    int b = (int)(g0 >> 11);
    int i0 = (int)(g0 & 2047);
    long row = g0 + rg*16 + l16;
    f32x4 acc[4];
    #pragma unroll
    for (int nf=0;nf<4;nf++) acc[nf] = (f32x4){0.f,0.f,0.f,0.f};
    #pragma unroll
    for (int ks=0; ks<8; ks++){
        int kb = ks*32 + khalf;
        const float4* hp = (const float4*)(h + row*FIn + kb);
        float4 h0 = hp[0], h1 = hp[1];
        short8 af;
        af[0]=(short)f2bf(h0.x); af[1]=(short)f2bf(h0.y); af[2]=(short)f2bf(h0.z); af[3]=(short)f2bf(h0.w);
        af[4]=(short)f2bf(h1.x); af[5]=(short)f2bf(h1.y); af[6]=(short)f2bf(h1.z); af[7]=(short)f2bf(h1.w);
        #pragma unroll
        for (int nf=0;nf<4;nf++){
            short8 bfv = *(const short8*)(WT + (ch*64 + nf*16 + l16)*FIn + kb);
            acc[nf] = __builtin_amdgcn_mfma_f32_16x16x32_bf16(af, bfv, acc[nf], 0, 0, 0);
        }
    }
    {
        float a1v[4], a2v[4];
        #pragma unroll
        for (int nf=0;nf<4;nf++){
            a1v[nf] = a[ch*64 + nf*16 + l16];
            a2v[nf] = a[FOn + ch*64 + nf*16 + l16];
        }
        #pragma unroll
        for (int r=0;r<4;r++){
            float u1 = 0.f, u2 = 0.f;
            #pragma unroll
            for (int nf=0;nf<4;nf++){ u1 = fmaf(acc[nf][r], a1v[nf], u1); u2 = fmaf(acc[nf][r], a2v[nf], u2); }
            u1 += __shfl_xor(u1, 1); u1 += __shfl_xor(u1, 2); u1 += __shfl_xor(u1, 4); u1 += __shfl_xor(u1, 8);
            u2 += __shfl_xor(u2, 1); u2 += __shfl_xor(u2, 2); u2 += __shfl_xor(u2, 4); u2 += __shfl_xor(u2, 8);
            if (l16 == 0){
                int rloc = rg*16 + ((lane>>4)<<2) + r;
                ps1[ch][rloc] = u1; ps2[ch][rloc] = u2;
            }
        }
    }
    int rbase = rg*16 + ((lane>>4)<<2);
    #pragma unroll
    for (int nf=0;nf<4;nf++)
        #pragma unroll
        for (int r=0;r<4;r++)
            tr[ch*64 + nf*16 + l16][rbase + r] = f2bf(acc[nf][r]);
    __syncthreads();
    if (t < 32){
        s1[g0 + t] = ps1[0][t] + ps1[1][t];
        s2[g0 + t] = ps2[0][t] + ps2[1][t];
    }
    int o = t >> 1, seg = t & 1;
    short8 v0 = *(const short8*)&tr[o][seg*16];
    short8 v1 = *(const short8*)&tr[o][seg*16 + 8];
    unsigned short* dst = WhT + ((long)(b*FOn + o))*Nn + i0 + seg*16;
    *(short8*)(dst)     = v0;
    *(short8*)(dst + 8) = v1;
}

// K2: s2max[b] = max_j s2[b][j]
__global__ __launch_bounds__(256) void k2_s2max(const float* __restrict__ s2, float* __restrict__ s2m){
    __shared__ float red[4];
    int b = blockIdx.x, t = threadIdx.x;
    float m = -1e30f;
    #pragma unroll
    for (int k=0;k<8;k++) m = fmaxf(m, s2[b*Nn + t + k*256]);
    m = fmaxf(m, __shfl_xor(m, 1));
    m = fmaxf(m, __shfl_xor(m, 2));
    m = fmaxf(m, __shfl_xor(m, 4));
    m = fmaxf(m, __shfl_xor(m, 8));
    m = fmaxf(m, __shfl_xor(m, 16));
    m = fmaxf(m, __shfl_xor(m, 32));
    if ((t & 63) == 0) red[t >> 6] = m;
    __syncthreads();
    if (t == 0) s2m[b] = fmaxf(fmaxf(red[0], red[1]), fmaxf(red[2], red[3]));
}

// K3 v8: round-4 skeleton + global-shift softmax (both previously PASSED).
// Block = (b, 32-row i-tile), 512 threads = 8 waves, grid 512 (2 blocks/CU).
// Single j-stream, 32 tiles of 64. V: reg-prefetch -> LDS parity dbuf.
// adj: depth-2 rotating register prefetch (r4-proven). s2: staged in LDS.
// Scores: p = adj ? exp(leaky(s1+s2)-Mx) : 0, Mx = leaky(s1+s2max[b]) (exact
// row upper bound; shift-invariant). No online state, no shfl chains, no
// rescale in loop. 1 barrier/tile. XCD pin: b = bid&7.
__global__ __launch_bounds__(512) void k3_flash(const int* __restrict__ adj,
        const unsigned short* __restrict__ WhT, const float* __restrict__ s1g,
        const float* __restrict__ s2g, const float* __restrict__ s2m,
        float* __restrict__ out){
    __shared__ __align__(16) unsigned short vt[2][128][72];
    __shared__ __align__(16) unsigned short pt[2][32][72];
    __shared__ float s2t[Nn];
    __shared__ float l_s[32];
    int t = threadIdx.x, lane = t & 63, w = t >> 6;
    int bid = blockIdx.x;
    int b = bid & 7;                 // XCD pin: per-b WhT slice resident in one L2
    int i0 = (bid >> 3) * 32;
    int q = t >> 4, c = t & 15;      // score row / col-group
    int rg = w >> 2, cq = w & 3;     // MFMA wave tile: rows rg*16.., cols cq*32..
    int l16 = lane & 15, khalf = (lane >> 4) * 8;
    *(float4*)&s2t[t*4] = *(const float4*)(s2g + b*Nn + t*4);
    float s1r = s1g[b*Nn + i0 + q];
    float Mx = s1r + s2m[b];
    Mx = fmaxf(Mx, 0.2f*Mx);         // leaky(s1r + s2max) >= every score in row
    // V depth-1 prefetch (rows vrow, vrow+64 at j-seg vj)
    int vrow = t >> 3, vj = (t & 7) * 8;
    const unsigned short* vp0 = WhT + ((long)(b*FOn + vrow))*Nn + vj;
    const unsigned short* vp1 = vp0 + 64*Nn;
    short8 vA0 = *(const short8*)(vp0);
    short8 vA1 = *(const short8*)(vp1);
    // adj depth-2 rotating prefetch
    const int* ajbase = adj + ((long)(b*Nn + i0 + q))*Nn + c*4;
    int4 ajA = *(const int4*)(ajbase);
    int4 ajB = *(const int4*)(ajbase + 64);
    float lsum = 0.f;
    f32x4 acc0 = (f32x4){0.f,0.f,0.f,0.f};
    f32x4 acc1 = (f32x4){0.f,0.f,0.f,0.f};
    __syncthreads();

    #pragma unroll 1
    for (int jt = 0; jt < 32; jt++){
        int j0 = jt*64;
        int par = jt & 1;
        // V regs -> LDS, re-issue next tile
        *(short8*)&vt[par][vrow][vj]      = vA0;
        *(short8*)&vt[par][vrow + 64][vj] = vA1;
        int jn = (jt < 31) ? j0 + 64 : j0;
        vA0 = *(const short8*)(vp0 + jn);
        vA1 = *(const short8*)(vp1 + jn);
        // adj rotating queue: consume A, shift B->A, issue jt+2
        int4 av = ajA; ajA = ajB;
        int jn2 = (jt < 30) ? j0 + 128 : j0;
        ajB = *(const int4*)(ajbase + jn2);
        // scores: global-shift softmax, no online state
        float4 s2c = *(const float4*)&s2t[j0 + c*4];
        float x0 = s1r + s2c.x; x0 = fmaxf(x0, 0.2f*x0);
        float x1 = s1r + s2c.y; x1 = fmaxf(x1, 0.2f*x1);
        float x2 = s1r + s2c.z; x2 = fmaxf(x2, 0.2f*x2);
        float x3 = s1r + s2c.w; x3 = fmaxf(x3, 0.2f*x3);
        float p0 = av.x > 0 ? __expf(x0 - Mx) : 0.f;
        float p1 = av.y > 0 ? __expf(x1 - Mx) : 0.f;
        float p2 = av.z > 0 ? __expf(x2 - Mx) : 0.f;
        float p3 = av.w > 0 ? __expf(x3 - Mx) : 0.f;
        lsum += (p0 + p1) + (p2 + p3);
        ushort4v pv;
        pv[0] = f2bf(p0); pv[1] = f2bf(p1); pv[2] = f2bf(p2); pv[3] = f2bf(p3);
        *(ushort4v*)&pt[par][q][c*4] = pv;
        __syncthreads();
        // MFMA (wave: rows rg*16..+15, cols cq*32..+31), no rescale
        #pragma unroll
        for (int kk=0;kk<2;kk++){
            short8 af = *(const short8*)&pt[par][rg*16 + l16][kk*32 + khalf];
            short8 b0 = *(const short8*)&vt[par][cq*32 + l16][kk*32 + khalf];
            short8 b1 = *(const short8*)&vt[par][cq*32 + 16 + l16][kk*32 + khalf];
            acc0 = __builtin_amdgcn_mfma_f32_16x16x32_bf16(af, b0, acc0, 0, 0, 0);
            acc1 = __builtin_amdgcn_mfma_f32_16x16x32_bf16(af, b1, acc1, 0, 0, 0);
        }
    }
    // single row-sum reduction for the whole kernel
    lsum += __shfl_xor(lsum, 1);
    lsum += __shfl_xor(lsum, 2);
    lsum += __shfl_xor(lsum, 4);
    lsum += __shfl_xor(lsum, 8);
    if (c == 0) l_s[q] = lsum;
    __syncthreads();
    // epilogue: /l, elu, store fp32
    int rb = rg*16 + ((lane>>4)<<2);
    #pragma unroll
    for (int reg=0;reg<4;reg++){
        int r = rb + reg;
        float inv = 1.f / l_s[r];
        float v0 = acc0[reg] * inv;
        float v1 = acc1[reg] * inv;
        v0 = v0 > 0.f ? v0 : (__expf(v0) - 1.f);
        v1 = v1 > 0.f ? v1 : (__expf(v1) - 1.f);
        out[((long)(b*Nn + i0 + r))*FOn + cq*32 + l16]      = v0;
        out[((long)(b*Nn + i0 + r))*FOn + cq*32 + 16 + l16] = v1;
    }
}

extern "C" void kernel_launch(void* const* d_in, const int* in_sizes, int n_in,
                              void* d_out, int out_size, void* d_ws, size_t ws_size,
                              hipStream_t stream){
    const float* h  = (const float*)d_in[0];
    const int* adj  = (const int*)d_in[1];
    const float* W  = (const float*)d_in[2];
    const float* a  = (const float*)d_in[3];
    float* out = (float*)d_out;
    char* ws = (char*)d_ws;
    unsigned short* WT  = (unsigned short*)(ws);                   //    65,536 B
    unsigned short* WhT = (unsigned short*)(ws + 65536);           // 4,194,304 B
    float* s1           = (float*)(ws + 65536 + 4194304);          //    65,536 B
    float* s2           = (float*)(ws + 65536 + 4194304 + 65536);  //    65,536 B
    float* s2m          = (float*)(ws + 65536 + 4194304 + 131072); //        32 B

    k0_wt    <<<128, 256, 0, stream>>>(W, WT);
    k1_gemm  <<<512, 256, 0, stream>>>(h, WT, a, WhT, s1, s2);
    k2_s2max <<<Bn,  256, 0, stream>>>(s2, s2m);
    k3_flash <<<512, 512, 0, stream>>>(adj, WhT, s1, s2, s2m, out);
}